// Round 11
// baseline (543.567 us; speedup 1.0000x reference)
//
#include <hip/hip_runtime.h>

// ---------------------------------------------------------------------------
// DensityEstimator: 3-layer neural spline flow inverse log-prob.
// R10: LU gemm + ident spline + odd-col transpose fused into lu_ident:
//      C-layout col parity == lm&1, lm-pair swap of j=2,3 payloads balances
//      spline work across all lanes; outputs identT[f][row] (bf16, coalesced),
//      zot[f][row] (fp32), ld row-partials via shuffle tree -> ldp[69..73].
//      z2 buffer / transpose_odd / ident_spline deleted; resnet stage-1 reads
//      identT; assemble sums 74 partials (32-row blocks). dend == 1.0 exact.
// ---------------------------------------------------------------------------

#define D_DIM 550
#define D_PAD 576
#define N_PAD_A 640
#define F_DIM 275
#define F_PAD 320
#define HID_DIM 128
#define OUT_DIM 6325
#define OUT_PAD 6400
#define FT_PAD 276
#define WO2_ROWS (FT_PAD*32)   // 8832 = 69*128
#define NCOLT 69               // wo_spline column tiles
#define NLDP (NCOLT+5)         // + 5 lu_ident col-tiles
#define B_ROWS 4096
#define NBINS 8
#define TB_C 3.0f
#define MINB_C 0.001f
#define MIND_C 0.001f
#define DCONST_C 0.53974233f
#define LUEPS_C 0.001f
#define RSQRT_HID 0.08838834764831845f

typedef unsigned short ushort_t;
typedef __attribute__((ext_vector_type(4))) unsigned short ushort4_t;
typedef __attribute__((ext_vector_type(8))) short short8;
typedef __attribute__((ext_vector_type(8))) unsigned short ushort8;
typedef __attribute__((ext_vector_type(4))) float f32x4;

__device__ __forceinline__ ushort_t f2bf(float f){
    union{float f; unsigned u;} v; v.f = f;
    unsigned r = v.u + 0x7fffu + ((v.u>>16)&1u);
    return (ushort_t)(r>>16);
}
__device__ __forceinline__ float bf2f(ushort_t h){
    union{unsigned u; float f;} v; v.u = ((unsigned)h)<<16;
    return v.f;
}
__device__ __forceinline__ float softplusf(float x){
    return fmaxf(x, 0.f) + __logf(1.f + __expf(-fabsf(x)));
}

__device__ __forceinline__ void knots_from_u(const float* u, float* c, float* w){
    float m = u[0];
#pragma unroll
    for(int k=1;k<NBINS;k++) m = fmaxf(m, u[k]);
    float e[NBINS]; float s = 0.f;
#pragma unroll
    for(int k=0;k<NBINS;k++){ e[k] = __expf(u[k]-m); s += e[k]; }
    float inv = 1.f/s;
    float cum = 0.f;
    c[0] = -TB_C;
#pragma unroll
    for(int k=0;k<NBINS;k++){
        float v = MINB_C + (1.f - MINB_C*(float)NBINS)*e[k]*inv;
        cum += v;
        c[k+1] = 2.f*TB_C*cum - TB_C;
    }
    c[NBINS] = TB_C;
#pragma unroll
    for(int k=0;k<NBINS;k++) w[k] = c[k+1]-c[k];
}

__device__ __forceinline__ void rqs_inv(float x,
                                        const float* cw, const float* w,
                                        const float* ch, const float* h,
                                        const float* d,
                                        float& out, float& ld){
    bool inside = (x >= -TB_C) && (x <= TB_C);
    float xi = fminf(fmaxf(x, -TB_C), TB_C);
    int idx = 0;
#pragma unroll
    for(int j=1;j<NBINS;j++) idx += (xi >= ch[j]) ? 1 : 0;
    float icw=cw[0], iw=w[0], ich=ch[0], ih=h[0], d0=d[0], d1=d[1];
#pragma unroll
    for(int j=1;j<NBINS;j++){
        if(idx==j){ icw=cw[j]; iw=w[j]; ich=ch[j]; ih=h[j]; d0=d[j]; d1=d[j+1]; }
    }
    float delta = ih/iw;
    float t  = xi - ich;
    float s  = d0 + d1 - 2.f*delta;
    float a  = t*s + ih*(delta - d0);
    float b  = ih*d0 - t*s;
    float c  = -delta*t;
    float disc = b*b - 4.f*a*c;
    float root = 2.f*c / (-b - sqrtf(fmaxf(disc, 0.f)));
    float o  = root*iw + icw;
    float tm = root*(1.f-root);
    float den  = delta + s*tm;
    float dnum = delta*delta*(d1*root*root + 2.f*delta*tm + d0*(1.f-root)*(1.f-root));
    float l = 2.f*__logf(den) - __logf(dnum);
    out = inside ? o : x;
    ld  = inside ? l : 0.f;
}

// --------------------------- setup kernels ---------------------------------

__global__ void build_knots_kernel(const float* __restrict__ uw_u,
                                   const float* __restrict__ uh_u,
                                   const float* __restrict__ ud_u,
                                   float* __restrict__ knots){
    int g = blockIdx.x*blockDim.x + threadIdx.x;
    if(g >= 3*F_DIM) return;
    float* kb = knots + (size_t)g*43;
    float c[9], w[8];
    knots_from_u(uw_u + (size_t)g*8, c, w);
#pragma unroll
    for(int k=0;k<9;k++) kb[k]=c[k];
#pragma unroll
    for(int k=0;k<8;k++) kb[9+k]=w[k];
    knots_from_u(uh_u + (size_t)g*8, c, w);
#pragma unroll
    for(int k=0;k<9;k++) kb[17+k]=c[k];
#pragma unroll
    for(int k=0;k<8;k++) kb[26+k]=w[k];
    kb[34]=1.0f; kb[42]=1.0f;   // MIND + softplus(DCONST) == 1 by construction
    const float* ud = ud_u + (size_t)g*7;
#pragma unroll
    for(int k=0;k<7;k++) kb[35+k] = MIND_C + softplusf(ud[k]);
}

__global__ void logdiag_kernel(const float* __restrict__ lu_ud, float* __restrict__ outv){
    int tid = threadIdx.x;
    float s = 0.f;
    for(int k=tid; k<3*D_DIM; k+=256) s += __logf(softplusf(lu_ud[k]) + LUEPS_C);
#pragma unroll
    for(int o=32;o>0;o>>=1) s += __shfl_down(s, o);
    __shared__ float sm[4];
    if((tid&63)==0) sm[tid>>6]=s;
    __syncthreads();
    if(tid==0) outv[0] = sm[0]+sm[1]+sm[2]+sm[3];
}

__global__ void build_LU_bf16(const float* __restrict__ lower,
                              const float* __restrict__ upper,
                              const float* __restrict__ ud,
                              const int* __restrict__ perm,
                              ushort_t* __restrict__ Lmb,
                              ushort_t* __restrict__ UpTb){
    int l = blockIdx.z;
    lower += (size_t)l*D_DIM*D_DIM; upper += (size_t)l*D_DIM*D_DIM;
    ud += (size_t)l*D_DIM; perm += (size_t)l*D_DIM;
    Lmb += (size_t)l*N_PAD_A*D_PAD; UpTb += (size_t)l*N_PAD_A*D_PAD;
    int k = blockIdx.x*blockDim.x + threadIdx.x;
    int j = blockIdx.y;
    if(k >= D_DIM) return;
    float lv = (j>k) ? lower[(size_t)j*D_DIM+k] : (j==k ? 1.f : 0.f);
    Lmb[(size_t)j*D_PAD+k] = f2bf(lv);
    float uv;
    if(j<k)       uv = upper[(size_t)j*D_DIM+k];
    else if(j==k) uv = softplusf(ud[k]) + LUEPS_C;
    else          uv = 0.f;
    UpTb[(size_t)perm[k]*D_PAD + j] = f2bf(uv);
}

__global__ void convert_pad(const float* __restrict__ in, ushort_t* __restrict__ out,
                            int M, int K, int Mpad, int Kpad){
    int idx = blockIdx.x*256 + threadIdx.x;
    if(idx >= Mpad*Kpad) return;
    int r = idx / Kpad, c = idx - r*Kpad;
    float v = (r<M && c<K) ? in[(size_t)r*K+c] : 0.f;
    out[idx] = f2bf(v);
}

template<int REMAP>
__global__ void transpose_convert(const float* __restrict__ in, ushort_t* __restrict__ out,
                                  int K, int N, int Kpad, int Npad, long s_in, long s_out){
    in += (size_t)blockIdx.z*s_in; out += (size_t)blockIdx.z*s_out;
    __shared__ float t[32][33];
    int kb = blockIdx.x*32, nb = blockIdx.y*32;
    int tx = threadIdx.x, ty = threadIdx.y;
#pragma unroll
    for(int i=0;i<32;i+=8){
        int k = kb+ty+i, n = nb+tx;
        t[ty+i][tx] = (k<K && n<N) ? in[(size_t)k*N+n] : 0.f;
    }
    __syncthreads();
#pragma unroll
    for(int i=0;i<32;i+=8){
        int n = nb+ty+i, k = kb+tx;
        if(REMAP){
            if(n < OUT_DIM && k < Kpad){
                int f = n/23, j = n - 23*f;
                out[(size_t)(f*32+j)*Kpad+k] = f2bf(t[tx][ty+i]);
            }
        } else if(n<Npad && k<Kpad){
            out[(size_t)n*Kpad+k] = f2bf(t[tx][ty+i]);
        }
    }
}

__global__ void reorder_bias(const float* __restrict__ bo, float* __restrict__ bo2){
    int idx = blockIdx.x*256 + threadIdx.x;
    if(idx >= 3*OUT_DIM) return;
    int l = idx/OUT_DIM, n = idx%OUT_DIM;
    int f = n/23, j = n - 23*f;
    bo2[(size_t)l*WO2_ROWS + f*32 + j] = bo[idx];
}

// ------------------------------ bf16 MFMA gemm (A-build only) --------------
template<int OUTBF, int XSWAP>
__global__ __launch_bounds__(256)
void gemm_mfma(const ushort_t* __restrict__ A, const ushort_t* __restrict__ Bt,
               const float* __restrict__ bias, void* __restrict__ Cv,
               int M, int N, int Kpad, long sA, long sB, long sC){
    A  += (size_t)blockIdx.z*sA;
    Bt += (size_t)blockIdx.z*sB;
    __shared__ ushort_t As[128][72];
    __shared__ ushort_t Bs[128][72];
    int tid = threadIdx.x;
    int row0 = (XSWAP ? blockIdx.x : blockIdx.y)*128;
    int col0 = (XSWAP ? blockIdx.y : blockIdx.x)*128;
    int wave = tid>>6, lane = tid&63;
    int wm = wave&1, wn = wave>>1;
    int lm = lane&15, quad = lane>>4;
    f32x4 acc[4][4] = {};
    for(int k0=0; k0<Kpad; k0+=64){
#pragma unroll
        for(int it=0; it<4; it++){
            int c = tid + it*256;
            int r = c>>3, c8 = (c&7)*8;
            *(ushort8*)&As[r][c8] = *(const ushort8*)(A + (size_t)(row0+r)*Kpad + k0 + c8);
            *(ushort8*)&Bs[r][c8] = *(const ushort8*)(Bt + (size_t)(col0+r)*Kpad + k0 + c8);
        }
        __syncthreads();
#pragma unroll
        for(int ks=0; ks<2; ks++){
            short8 af[4], bfr[4];
#pragma unroll
            for(int i=0;i<4;i++){
                af[i]  = *(const short8*)&As[wm*64 + i*16 + lm][ks*32 + quad*8];
                bfr[i] = *(const short8*)&Bs[wn*64 + i*16 + lm][ks*32 + quad*8];
            }
#pragma unroll
            for(int i=0;i<4;i++)
#pragma unroll
                for(int j=0;j<4;j++)
                    acc[i][j] = __builtin_amdgcn_mfma_f32_16x16x32_bf16(af[i], bfr[j], acc[i][j], 0, 0, 0);
        }
        __syncthreads();
    }
#pragma unroll
    for(int i=0;i<4;i++){
        int rbase = row0 + wm*64 + i*16 + quad*4;
#pragma unroll
        for(int j=0;j<4;j++){
            int gc = col0 + wn*64 + j*16 + lm;
            if(gc >= N) continue;
            float bv = bias[gc];
#pragma unroll
            for(int r=0;r<4;r++){
                int gr = rbase + r;
                float v = acc[i][j][r] + bv;
                if(OUTBF) ((ushort_t*)Cv + (size_t)blockIdx.z*sC)[(size_t)gr*N+gc] = f2bf(v);
                else      ((float*)Cv + (size_t)blockIdx.z*sC)[(size_t)gr*N+gc] = v;
            }
        }
    }
}

// ----------------- fused LU gemm + ident spline + odd transpose ------------
// Grid (32 row-tiles, 5 col-tiles). Even cols -> rqs(knots) -> identT[f][row];
// odd cols -> zot[f][row]. lm-pair swap of j=2,3 payloads balances work.
__global__ __launch_bounds__(256)
void lu_ident(const ushort_t* __restrict__ A,      // z bf16 [4096][D_PAD]
              const ushort_t* __restrict__ Bt,     // Apb layer [640][D_PAD]
              const float* __restrict__ lub,       // [550]
              const float* __restrict__ knots,     // layer base, [F_DIM][43]
              ushort_t* __restrict__ identT,       // [F_PAD][B_ROWS]
              float* __restrict__ zot,             // [F_DIM][B_ROWS]
              float* __restrict__ ldp){            // rows NCOLT..NCOLT+4
    __shared__ ushort_t As[128][72];
    __shared__ ushort_t Bs[128][72];
    __shared__ float ldacc[2][128];
    int tid = threadIdx.x;
    int row0 = blockIdx.x*128, col0 = blockIdx.y*128;
    int wave = tid>>6, lane = tid&63;
    int wm = wave&1, wn = wave>>1;
    int lm = lane&15, quad = lane>>4;
    f32x4 acc[4][4] = {};
    for(int k0=0; k0<D_PAD; k0+=64){
#pragma unroll
        for(int it=0; it<4; it++){
            int c = tid + it*256;
            int r = c>>3, c8 = (c&7)*8;
            *(ushort8*)&As[r][c8] = *(const ushort8*)(A + (size_t)(row0+r)*D_PAD + k0 + c8);
            *(ushort8*)&Bs[r][c8] = *(const ushort8*)(Bt + (size_t)(col0+r)*D_PAD + k0 + c8);
        }
        __syncthreads();
#pragma unroll
        for(int ks=0; ks<2; ks++){
            short8 af[4], bfr[4];
#pragma unroll
            for(int i=0;i<4;i++){
                af[i]  = *(const short8*)&As[wm*64 + i*16 + lm][ks*32 + quad*8];
                bfr[i] = *(const short8*)&Bs[wn*64 + i*16 + lm][ks*32 + quad*8];
            }
#pragma unroll
            for(int i=0;i<4;i++)
#pragma unroll
                for(int j=0;j<4;j++)
                    acc[i][j] = __builtin_amdgcn_mfma_f32_16x16x32_bf16(af[i], bfr[j], acc[i][j], 0, 0, 0);
        }
        __syncthreads();
    }
    // swap j=2,3 payloads with lane^1 (work balance: every lane gets
    // 2 even-col feature groups + 2 odd-col store groups)
    f32x4 accs[4][2];
#pragma unroll
    for(int i=0;i<4;i++)
#pragma unroll
        for(int j=0;j<2;j++)
#pragma unroll
            for(int r=0;r<4;r++)
                accs[i][j][r] = __shfl_xor(acc[i][2+j][r], 1);
    float rowld[4][4] = {};
#pragma unroll
    for(int j=0;j<4;j++){
        int elm = (j<2) ? lm : (lm^1);
        int gc = col0 + wn*64 + j*16 + elm;
        if(gc < D_DIM){
            float bv = lub[gc];
            int f = gc>>1;
            if((gc&1)==0){
                const float* kb = knots + (size_t)f*43;
#pragma unroll
                for(int i=0;i<4;i++){
                    int gr0 = row0 + wm*64 + i*16 + quad*4;
                    ushort4_t o4;
#pragma unroll
                    for(int r=0;r<4;r++){
                        float v = ((j<2)?acc[i][j][r]:accs[i][j-2][r]) + bv;
                        float o, l;
                        rqs_inv(v, kb, kb+9, kb+17, kb+26, kb+34, o, l);
                        o4[r] = f2bf(o);
                        rowld[i][r] += l;
                    }
                    *(ushort4_t*)&identT[(size_t)f*B_ROWS + gr0] = o4;
                }
            } else {
#pragma unroll
                for(int i=0;i<4;i++){
                    int gr0 = row0 + wm*64 + i*16 + quad*4;
                    f32x4 vv;
#pragma unroll
                    for(int r=0;r<4;r++) vv[r] = ((j<2)?acc[i][j][r]:accs[i][j-2][r]) + bv;
                    *(f32x4*)&zot[(size_t)f*B_ROWS + gr0] = vv;
                }
            }
        }
    }
    // per-row ld reduction across 16-lane lm group
#pragma unroll
    for(int i=0;i<4;i++)
#pragma unroll
        for(int r=0;r<4;r++){
            float v = rowld[i][r];
            v += __shfl_xor(v,1); v += __shfl_xor(v,2);
            v += __shfl_xor(v,4); v += __shfl_xor(v,8);
            if(lm==0) ldacc[wn][wm*64 + i*16 + quad*4 + r] = v;
        }
    __syncthreads();
    if(tid < 128)
        ldp[(size_t)(NCOLT + blockIdx.y)*B_ROWS + row0 + tid] = ldacc[0][tid] + ldacc[1][tid];
}

// ------------------------------ fused resnet -------------------------------
__global__ __launch_bounds__(256)
void resnet_fused(const ushort_t* __restrict__ identT,  // [F_PAD][B_ROWS]
                  const ushort_t* __restrict__ WiT,
                  const float* __restrict__ bi,
                  const ushort_t* __restrict__ WbT,
                  const float* __restrict__ bb,
                  ushort_t* __restrict__ tb){
    __shared__ __align__(16) char smem[(64*136 + 128*136)*2];
    ushort_t (*As2)[136] = (ushort_t(*)[136])smem;
    ushort_t (*Ws)[136]  = (ushort_t(*)[136])(smem + 64*136*2);
    ushort_t (*As1)[72]  = (ushort_t(*)[72])smem;
    ushort_t (*Bs1)[72]  = (ushort_t(*)[72])(smem + 64*136*2);
    int tid = threadIdx.x, wave = tid>>6, lane = tid&63;
    int lm = lane&15, quad = lane>>4;
    int r0 = blockIdx.x*64;
    f32x4 cur[8] = {};
    f32x4 tsv[8];
    for(int k0=0; k0<F_PAD; k0+=64){
#pragma unroll
        for(int it=0; it<2; it++){
            int v = tid + it*256; int kk = v>>3, c8 = (v&7)*8;
            ushort8 u = *(const ushort8*)(identT + (size_t)(k0+kk)*B_ROWS + r0 + c8);
#pragma unroll
            for(int e=0;e<8;e++) As1[c8+e][kk] = u[e];   // As1[row][feat]
        }
#pragma unroll
        for(int it=0; it<4; it++){
            int v = tid + it*256; int n = v>>3, c8 = (v&7)*8;
            *(ushort8*)&Bs1[n][c8] = *(const ushort8*)(WiT + (size_t)n*F_PAD + k0 + c8);
        }
        __syncthreads();
#pragma unroll
        for(int ks=0; ks<2; ks++){
            short8 af = *(const short8*)&As1[wave*16 + lm][ks*32 + quad*8];
#pragma unroll
            for(int j=0;j<8;j++){
                short8 bf = *(const short8*)&Bs1[j*16 + lm][ks*32 + quad*8];
                cur[j] = __builtin_amdgcn_mfma_f32_16x16x32_bf16(af, bf, cur[j], 0, 0, 0);
            }
        }
        __syncthreads();
    }
#pragma unroll
    for(int j=0;j<8;j++){
        float bv = bi[j*16 + lm];
#pragma unroll
        for(int r=0;r<4;r++) cur[j][r] += bv;
        tsv[j] = cur[j];
    }
    for(int st=0; st<4; st++){
#pragma unroll
        for(int j=0;j<8;j++)
#pragma unroll
            for(int r=0;r<4;r++)
                As2[wave*16 + quad*4 + r][j*16 + lm] = f2bf(fmaxf(cur[j][r], 0.f));
#pragma unroll
        for(int it=0; it<8; it++){
            int v = tid + it*256; int n = v>>4, c8 = (v&15)*8;
            *(ushort8*)&Ws[n][c8] = *(const ushort8*)(WbT + (size_t)st*128*128 + (size_t)n*128 + c8);
        }
        __syncthreads();
        f32x4 acc[8] = {};
#pragma unroll
        for(int ks=0; ks<4; ks++){
            short8 af = *(const short8*)&As2[wave*16 + lm][ks*32 + quad*8];
#pragma unroll
            for(int j=0;j<8;j++){
                short8 bf = *(const short8*)&Ws[j*16 + lm][ks*32 + quad*8];
                acc[j] = __builtin_amdgcn_mfma_f32_16x16x32_bf16(af, bf, acc[j], 0, 0, 0);
            }
        }
        __syncthreads();
#pragma unroll
        for(int j=0;j<8;j++){
            float bv = bb[st*128 + j*16 + lm];
#pragma unroll
            for(int r=0;r<4;r++) acc[j][r] += bv;
        }
        if(st==1 || st==3){
#pragma unroll
            for(int j=0;j<8;j++){
#pragma unroll
                for(int r=0;r<4;r++) acc[j][r] += tsv[j][r];
                tsv[j] = acc[j];
            }
        }
#pragma unroll
        for(int j=0;j<8;j++) cur[j] = acc[j];
    }
#pragma unroll
    for(int j=0;j<8;j++)
#pragma unroll
        for(int r=0;r<4;r++)
            tb[(size_t)(r0 + wave*16 + quad*4 + r)*HID_DIM + j*16 + lm] = f2bf(cur[j][r]);
}

// ----------------------- fused Wo gemm + trans spline ----------------------
__global__ __launch_bounds__(256)
void wo_spline(const ushort_t* __restrict__ tb,
               const ushort_t* __restrict__ Wo2,
               const float* __restrict__ bo2,
               const float* __restrict__ zot,
               ushort_t* __restrict__ tout,
               float* __restrict__ ldp){
    __shared__ __align__(16) char smem[128*72*2*2];
    __shared__ float ldred[128];
    ushort_t (*As)[72] = (ushort_t(*)[72])smem;
    ushort_t (*Bs)[72] = (ushort_t(*)[72])(smem + 128*72*2);
    ushort_t (*P)[138] = (ushort_t(*)[138])smem;
    int tid = threadIdx.x;
    int row0 = blockIdx.x*128;
    int colt = blockIdx.y;
    int col0 = colt*128;
    int wave = tid>>6, lane = tid&63;
    int wm = wave&1, wn = wave>>1;
    int lm = lane&15, quad = lane>>4;
    f32x4 acc[4][4] = {};
    for(int k0=0; k0<HID_DIM; k0+=64){
#pragma unroll
        for(int it=0; it<4; it++){
            int c = tid + it*256;
            int r = c>>3, c8 = (c&7)*8;
            *(ushort8*)&As[r][c8] = *(const ushort8*)(tb + (size_t)(row0+r)*HID_DIM + k0 + c8);
            *(ushort8*)&Bs[r][c8] = *(const ushort8*)(Wo2 + (size_t)(col0+r)*HID_DIM + k0 + c8);
        }
        __syncthreads();
#pragma unroll
        for(int ks=0; ks<2; ks++){
            short8 af[4], bfr[4];
#pragma unroll
            for(int i=0;i<4;i++){
                af[i]  = *(const short8*)&As[wm*64 + i*16 + lm][ks*32 + quad*8];
                bfr[i] = *(const short8*)&Bs[wn*64 + i*16 + lm][ks*32 + quad*8];
            }
#pragma unroll
            for(int i=0;i<4;i++)
#pragma unroll
                for(int j=0;j<4;j++)
                    acc[i][j] = __builtin_amdgcn_mfma_f32_16x16x32_bf16(af[i], bfr[j], acc[i][j], 0, 0, 0);
        }
        __syncthreads();
    }
#pragma unroll
    for(int j=0;j<4;j++){
        int cl = wn*64 + j*16 + lm;
        float bv = bo2[col0 + cl];
#pragma unroll
        for(int i=0;i<4;i++){
            int rl = wm*64 + i*16 + quad*4;
#pragma unroll
            for(int r=0;r<4;r++) P[rl+r][cl] = f2bf(acc[i][j][r] + bv);
        }
    }
    __syncthreads();
    int row = tid & 127;
    int fbase = colt*4;
    float ldsum = 0.f;
#pragma unroll
    for(int e=0;e<2;e++){
        int feat = (tid>>7) + e*2;
        int fg = fbase + feat;
        if(fg < F_DIM){
            float xv = zot[(size_t)fg*B_ROWS + row0 + row];
            const ushort_t* q = &P[row][feat*32];
            float uw[8], uh[8];
#pragma unroll
            for(int c=0;c<8;c++){ uw[c] = bf2f(q[c])*RSQRT_HID; uh[c] = bf2f(q[8+c])*RSQRT_HID; }
            float cw[9], w[8], ch[9], h[8], d[9];
            knots_from_u(uw, cw, w);
            knots_from_u(uh, ch, h);
            d[0]=1.0f; d[8]=1.0f;
#pragma unroll
            for(int c=0;c<7;c++) d[c+1] = MIND_C + softplusf(bf2f(q[16+c]));
            float o, l;
            rqs_inv(xv, cw, w, ch, h, d, o, l);
            tout[(size_t)fg*B_ROWS + row0 + row] = f2bf(o);
            ldsum += l;
        }
    }
    if(tid >= 128) ldred[tid-128] = ldsum;
    __syncthreads();
    if(tid < 128) ldp[(size_t)colt*B_ROWS + row0 + tid] = ldsum + ldred[tid];
}

// ------------------------------ assemble -----------------------------------
// 32-row blocks (grid 128). znb[r][2f]=identT[f][r]; znb[r][2f+1]=tout[f][r];
// lq[r] += sum_j ldp[j][r] over all 74 partials.
__global__ __launch_bounds__(256)
void assemble_kernel(const ushort_t* __restrict__ identT,
                     const ushort_t* __restrict__ tout,
                     const float* __restrict__ ldp,
                     ushort_t* __restrict__ znb,
                     float* __restrict__ lq){
    __shared__ ushort_t T[F_DIM][33];
    __shared__ ushort_t I[F_DIM][33];
    int r0 = blockIdx.x*32;
    int tid = threadIdx.x;
    for(int idx = tid; idx < F_DIM*32; idx += 256){
        int f = idx>>5, r = idx&31;
        T[f][r] = tout[(size_t)f*B_ROWS + r0 + r];
        I[f][r] = identT[(size_t)f*B_ROWS + r0 + r];
    }
    float s = 0.f;
    if(tid < 32){
        for(int j=0;j<NLDP;j++) s += ldp[(size_t)j*B_ROWS + r0 + tid];
    }
    __syncthreads();
    if(tid < 32) lq[r0+tid] += s;
    for(int sidx = tid; sidx < 32*(D_PAD/8); sidx += 256){
        int row = sidx/(D_PAD/8), c8 = sidx%(D_PAD/8);
        int colb = c8*8;
        ushort_t u[8];
#pragma unroll
        for(int k=0;k<8;k++){
            int col = colb + k;
            ushort_t v = 0;
            if(col < D_DIM){
                int f = col>>1;
                v = (col&1) ? T[f][row] : I[f][row];
            }
            u[k] = v;
        }
        *(ushort8*)&znb[(size_t)(r0+row)*D_PAD + colb] = *(ushort8*)u;
    }
}

// ------------------------------ finalize -----------------------------------
__global__ __launch_bounds__(320)
void finalize_kernel(const ushort_t* __restrict__ zb, const float* __restrict__ loc,
                     const float* __restrict__ lsc, const float* __restrict__ lq,
                     const float* __restrict__ logdiag, float* __restrict__ out){
    int row = blockIdx.x; int tid = threadIdx.x;
    float s = 0.f;
    for(int k=tid; k<D_DIM; k+=320){
        float l = lsc[k];
        float diff = (bf2f(zb[(size_t)row*D_PAD+k])-loc[k])*__expf(-l);
        s += l + 0.5f*diff*diff;
    }
    __shared__ float sm[5];
#pragma unroll
    for(int o=32;o>0;o>>=1) s += __shfl_down(s, o);
    if((tid&63)==0) sm[tid>>6]=s;
    __syncthreads();
    if(tid==0){
        float tot = sm[0]+sm[1]+sm[2]+sm[3]+sm[4];
        out[row] = lq[row] + logdiag[0] - 275.f*1.8378770664f - tot;
    }
}

// ---------------------------------------------------------------------------

extern "C" void kernel_launch(void* const* d_in, const int* in_sizes, int n_in,
                              void* d_out, int out_size, void* d_ws, size_t ws_size,
                              hipStream_t stream){
    const float* x        = (const float*)d_in[0];
    const float* loc      = (const float*)d_in[1];
    const float* lsc      = (const float*)d_in[2];
    const float* Wi       = (const float*)d_in[3];
    const float* bi       = (const float*)d_in[4];
    const float* Wb       = (const float*)d_in[5];
    const float* bb       = (const float*)d_in[6];
    const float* Wo       = (const float*)d_in[7];
    const float* bo       = (const float*)d_in[8];
    const float* uw_u     = (const float*)d_in[9];
    const float* uh_u     = (const float*)d_in[10];
    const float* ud_u     = (const float*)d_in[11];
    const float* lu_lower = (const float*)d_in[12];
    const float* lu_upper = (const float*)d_in[13];
    const float* lu_ud    = (const float*)d_in[14];
    const float* lu_b     = (const float*)d_in[15];
    const int*   perms    = (const int*)d_in[16];
    float* out = (float*)d_out;

    char* base = (char*)d_ws;
    size_t off = 0;
    auto alloc = [&](size_t bytes)->char*{
        char* p = base + off;
        off += (bytes + 255) & ~(size_t)255;
        return p;
    };
    float* lq      = (float*)alloc(B_ROWS*4);
    float* zbias   = (float*)alloc(D_PAD*4);
    float* logdiag = (float*)alloc(64*4);
    float* knots   = (float*)alloc((size_t)3*F_DIM*43*4);
    float* zot     = (float*)alloc((size_t)F_DIM*B_ROWS*4);
    float* bo2     = (float*)alloc((size_t)3*WO2_ROWS*4);
    float* ldp     = (float*)alloc((size_t)NLDP*B_ROWS*4);
    ushort_t* xb   = (ushort_t*)alloc((size_t)B_ROWS*D_PAD*2);
    ushort_t* zbf0 = (ushort_t*)alloc((size_t)B_ROWS*D_PAD*2);
    ushort_t* zbf1 = (ushort_t*)alloc((size_t)B_ROWS*D_PAD*2);
    ushort_t* identT=(ushort_t*)alloc((size_t)F_PAD*B_ROWS*2);
    ushort_t* tout = (ushort_t*)alloc((size_t)F_DIM*B_ROWS*2);
    ushort_t* Lmb  = (ushort_t*)alloc((size_t)3*N_PAD_A*D_PAD*2);
    ushort_t* UpTb = (ushort_t*)alloc((size_t)3*N_PAD_A*D_PAD*2);
    ushort_t* Apb  = (ushort_t*)alloc((size_t)3*N_PAD_A*D_PAD*2);
    ushort_t* tb   = (ushort_t*)alloc((size_t)B_ROWS*HID_DIM*2);
    ushort_t* WiT  = (ushort_t*)alloc((size_t)3*HID_DIM*F_PAD*2);
    ushort_t* WbT  = (ushort_t*)alloc((size_t)3*4*HID_DIM*HID_DIM*2);
    ushort_t* Wo2  = (ushort_t*)alloc((size_t)3*WO2_ROWS*HID_DIM*2);

    hipMemsetAsync(lq, 0, B_ROWS*sizeof(float), stream);
    hipMemsetAsync(zbias, 0, D_PAD*sizeof(float), stream);
    hipMemsetAsync(Lmb, 0, (size_t)3*N_PAD_A*D_PAD*2, stream);
    hipMemsetAsync(UpTb, 0, (size_t)3*N_PAD_A*D_PAD*2, stream);
    hipMemsetAsync(Wo2, 0, (size_t)3*WO2_ROWS*HID_DIM*2, stream);
    hipMemsetAsync(bo2, 0, (size_t)3*WO2_ROWS*4, stream);
    // identT pad rows (275..319) must be zero for resnet K=320 staging
    hipMemsetAsync(identT + (size_t)F_DIM*B_ROWS, 0, (size_t)(F_PAD-F_DIM)*B_ROWS*2, stream);
    build_knots_kernel<<<dim3((3*F_DIM+255)/256), dim3(256), 0, stream>>>(uw_u, uh_u, ud_u, knots);
    logdiag_kernel<<<dim3(1), dim3(256), 0, stream>>>(lu_ud, logdiag);
    convert_pad<<<dim3((B_ROWS*D_PAD+255)/256), dim3(256), 0, stream>>>(
        x, xb, B_ROWS, D_DIM, B_ROWS, D_PAD);
    build_LU_bf16<<<dim3((D_DIM+255)/256, D_DIM, 3), dim3(256), 0, stream>>>(
        lu_lower, lu_upper, lu_ud, perms, Lmb, UpTb);
    gemm_mfma<1,0><<<dim3(5, 5, 3), dim3(256), 0, stream>>>(
        Lmb, UpTb, zbias, Apb, N_PAD_A, D_PAD, D_PAD,
        (long)N_PAD_A*D_PAD, (long)N_PAD_A*D_PAD, (long)N_PAD_A*D_PAD);
    dim3 tthr(32,8);
    transpose_convert<0><<<dim3(F_PAD/32, HID_DIM/32, 3), tthr, 0, stream>>>(
        Wi, WiT, F_DIM, HID_DIM, F_PAD, HID_DIM, (long)F_DIM*HID_DIM, (long)F_PAD*HID_DIM);
    transpose_convert<0><<<dim3(HID_DIM/32, HID_DIM/32, 12), tthr, 0, stream>>>(
        Wb, WbT, HID_DIM, HID_DIM, HID_DIM, HID_DIM, (long)HID_DIM*HID_DIM, (long)HID_DIM*HID_DIM);
    transpose_convert<1><<<dim3(HID_DIM/32, OUT_PAD/32, 3), tthr, 0, stream>>>(
        Wo, Wo2, HID_DIM, OUT_DIM, HID_DIM, OUT_PAD, (long)HID_DIM*OUT_DIM, (long)WO2_ROWS*HID_DIM);
    reorder_bias<<<dim3((3*OUT_DIM+255)/256), dim3(256), 0, stream>>>(bo, bo2);

    const ushort_t* zcur_b = xb;
    ushort_t* zbf[2] = {zbf0, zbf1};
    int zi = 0;

    for(int it=0; it<3; ++it){
        int i = 2 - it;

        lu_ident<<<dim3(B_ROWS/128, N_PAD_A/128), dim3(256), 0, stream>>>(
            zcur_b, Apb + (size_t)i*N_PAD_A*D_PAD, lu_b + (size_t)i*D_DIM,
            knots + (size_t)i*F_DIM*43, identT, zot, ldp);

        resnet_fused<<<dim3(B_ROWS/64), dim3(256), 0, stream>>>(
            identT, WiT + (size_t)i*HID_DIM*F_PAD, bi + (size_t)i*HID_DIM,
            WbT + (size_t)i*4*HID_DIM*HID_DIM, bb + (size_t)i*4*HID_DIM, tb);

        wo_spline<<<dim3(B_ROWS/128, NCOLT), dim3(256), 0, stream>>>(
            tb, Wo2 + (size_t)i*WO2_ROWS*HID_DIM, bo2 + (size_t)i*WO2_ROWS,
            zot, tout, ldp);

        assemble_kernel<<<dim3(B_ROWS/32), dim3(256), 0, stream>>>(
            identT, tout, ldp, zbf[zi], lq);

        zcur_b = zbf[zi];
        zi ^= 1;
    }

    finalize_kernel<<<dim3(B_ROWS), dim3(320), 0, stream>>>(
        zcur_b, loc, lsc, lq, logdiag, out);
}

// Round 12
// 485.083 us; speedup vs baseline: 1.1206x; 1.1206x over previous
//
#include <hip/hip_runtime.h>

// ---------------------------------------------------------------------------
// DensityEstimator: 3-layer neural spline flow inverse log-prob.
// R11: revert R10's lu_ident fusion (160-block grid starved 37% of CUs,
//      occupancy 6%). Back to R9 structure + one change: wo_spline gets
//      __launch_bounds__(256,2) -> VGPR cap 256. R7-R10 counters show
//      ~60MB/dispatch phantom WRITE+FETCH = scratch spills of the spline's
//      ~60 live floats at the compiler's VGPR=72 choice. LDS (37KB, 4
//      blocks/CU) stays the occupancy limiter, so no occupancy loss.
// ---------------------------------------------------------------------------

#define D_DIM 550
#define D_PAD 576
#define N_PAD_A 640
#define F_DIM 275
#define F_PAD 320
#define HID_DIM 128
#define OUT_DIM 6325
#define OUT_PAD 6400
#define FT_PAD 276
#define WO2_ROWS (FT_PAD*32)   // 8832 = 69*128
#define NCOLT 69
#define B_ROWS 4096
#define NBINS 8
#define TB_C 3.0f
#define MINB_C 0.001f
#define MIND_C 0.001f
#define DCONST_C 0.53974233f
#define LUEPS_C 0.001f
#define RSQRT_HID 0.08838834764831845f

typedef unsigned short ushort_t;
typedef __attribute__((ext_vector_type(8))) short short8;
typedef __attribute__((ext_vector_type(8))) unsigned short ushort8;
typedef __attribute__((ext_vector_type(4))) float f32x4;

__device__ __forceinline__ ushort_t f2bf(float f){
    union{float f; unsigned u;} v; v.f = f;
    unsigned r = v.u + 0x7fffu + ((v.u>>16)&1u);
    return (ushort_t)(r>>16);
}
__device__ __forceinline__ float bf2f(ushort_t h){
    union{unsigned u; float f;} v; v.u = ((unsigned)h)<<16;
    return v.f;
}
__device__ __forceinline__ float softplusf(float x){
    return fmaxf(x, 0.f) + __logf(1.f + __expf(-fabsf(x)));
}

__device__ __forceinline__ void knots_from_u(const float* u, float* c, float* w){
    float m = u[0];
#pragma unroll
    for(int k=1;k<NBINS;k++) m = fmaxf(m, u[k]);
    float e[NBINS]; float s = 0.f;
#pragma unroll
    for(int k=0;k<NBINS;k++){ e[k] = __expf(u[k]-m); s += e[k]; }
    float inv = 1.f/s;
    float cum = 0.f;
    c[0] = -TB_C;
#pragma unroll
    for(int k=0;k<NBINS;k++){
        float v = MINB_C + (1.f - MINB_C*(float)NBINS)*e[k]*inv;
        cum += v;
        c[k+1] = 2.f*TB_C*cum - TB_C;
    }
    c[NBINS] = TB_C;
#pragma unroll
    for(int k=0;k<NBINS;k++) w[k] = c[k+1]-c[k];
}

__device__ __forceinline__ void rqs_inv(float x,
                                        const float* cw, const float* w,
                                        const float* ch, const float* h,
                                        const float* d,
                                        float& out, float& ld){
    bool inside = (x >= -TB_C) && (x <= TB_C);
    float xi = fminf(fmaxf(x, -TB_C), TB_C);
    int idx = 0;
#pragma unroll
    for(int j=1;j<NBINS;j++) idx += (xi >= ch[j]) ? 1 : 0;
    float icw=cw[0], iw=w[0], ich=ch[0], ih=h[0], d0=d[0], d1=d[1];
#pragma unroll
    for(int j=1;j<NBINS;j++){
        if(idx==j){ icw=cw[j]; iw=w[j]; ich=ch[j]; ih=h[j]; d0=d[j]; d1=d[j+1]; }
    }
    float delta = ih/iw;
    float t  = xi - ich;
    float s  = d0 + d1 - 2.f*delta;
    float a  = t*s + ih*(delta - d0);
    float b  = ih*d0 - t*s;
    float c  = -delta*t;
    float disc = b*b - 4.f*a*c;
    float root = 2.f*c / (-b - sqrtf(fmaxf(disc, 0.f)));
    float o  = root*iw + icw;
    float tm = root*(1.f-root);
    float den  = delta + s*tm;
    float dnum = delta*delta*(d1*root*root + 2.f*delta*tm + d0*(1.f-root)*(1.f-root));
    float l = 2.f*__logf(den) - __logf(dnum);
    out = inside ? o : x;
    ld  = inside ? l : 0.f;
}

// --------------------------- setup kernels ---------------------------------

__global__ void build_knots_kernel(const float* __restrict__ uw_u,
                                   const float* __restrict__ uh_u,
                                   const float* __restrict__ ud_u,
                                   float* __restrict__ knots){
    int g = blockIdx.x*blockDim.x + threadIdx.x;
    if(g >= 3*F_DIM) return;
    float* kb = knots + (size_t)g*43;
    float c[9], w[8];
    knots_from_u(uw_u + (size_t)g*8, c, w);
#pragma unroll
    for(int k=0;k<9;k++) kb[k]=c[k];
#pragma unroll
    for(int k=0;k<8;k++) kb[9+k]=w[k];
    knots_from_u(uh_u + (size_t)g*8, c, w);
#pragma unroll
    for(int k=0;k<9;k++) kb[17+k]=c[k];
#pragma unroll
    for(int k=0;k<8;k++) kb[26+k]=w[k];
    kb[34]=1.0f; kb[42]=1.0f;   // MIND + softplus(DCONST) == 1 by construction
    const float* ud = ud_u + (size_t)g*7;
#pragma unroll
    for(int k=0;k<7;k++) kb[35+k] = MIND_C + softplusf(ud[k]);
}

__global__ void logdiag_kernel(const float* __restrict__ lu_ud, float* __restrict__ outv){
    int tid = threadIdx.x;
    float s = 0.f;
    for(int k=tid; k<3*D_DIM; k+=256) s += __logf(softplusf(lu_ud[k]) + LUEPS_C);
#pragma unroll
    for(int o=32;o>0;o>>=1) s += __shfl_down(s, o);
    __shared__ float sm[4];
    if((tid&63)==0) sm[tid>>6]=s;
    __syncthreads();
    if(tid==0) outv[0] = sm[0]+sm[1]+sm[2]+sm[3];
}

__global__ void build_LU_bf16(const float* __restrict__ lower,
                              const float* __restrict__ upper,
                              const float* __restrict__ ud,
                              const int* __restrict__ perm,
                              ushort_t* __restrict__ Lmb,
                              ushort_t* __restrict__ UpTb){
    int l = blockIdx.z;
    lower += (size_t)l*D_DIM*D_DIM; upper += (size_t)l*D_DIM*D_DIM;
    ud += (size_t)l*D_DIM; perm += (size_t)l*D_DIM;
    Lmb += (size_t)l*N_PAD_A*D_PAD; UpTb += (size_t)l*N_PAD_A*D_PAD;
    int k = blockIdx.x*blockDim.x + threadIdx.x;
    int j = blockIdx.y;
    if(k >= D_DIM) return;
    float lv = (j>k) ? lower[(size_t)j*D_DIM+k] : (j==k ? 1.f : 0.f);
    Lmb[(size_t)j*D_PAD+k] = f2bf(lv);
    float uv;
    if(j<k)       uv = upper[(size_t)j*D_DIM+k];
    else if(j==k) uv = softplusf(ud[k]) + LUEPS_C;
    else          uv = 0.f;
    UpTb[(size_t)perm[k]*D_PAD + j] = f2bf(uv);
}

__global__ void convert_pad(const float* __restrict__ in, ushort_t* __restrict__ out,
                            int M, int K, int Mpad, int Kpad){
    int idx = blockIdx.x*256 + threadIdx.x;
    if(idx >= Mpad*Kpad) return;
    int r = idx / Kpad, c = idx - r*Kpad;
    float v = (r<M && c<K) ? in[(size_t)r*K+c] : 0.f;
    out[idx] = f2bf(v);
}

template<int REMAP>
__global__ void transpose_convert(const float* __restrict__ in, ushort_t* __restrict__ out,
                                  int K, int N, int Kpad, int Npad, long s_in, long s_out){
    in += (size_t)blockIdx.z*s_in; out += (size_t)blockIdx.z*s_out;
    __shared__ float t[32][33];
    int kb = blockIdx.x*32, nb = blockIdx.y*32;
    int tx = threadIdx.x, ty = threadIdx.y;
#pragma unroll
    for(int i=0;i<32;i+=8){
        int k = kb+ty+i, n = nb+tx;
        t[ty+i][tx] = (k<K && n<N) ? in[(size_t)k*N+n] : 0.f;
    }
    __syncthreads();
#pragma unroll
    for(int i=0;i<32;i+=8){
        int n = nb+ty+i, k = kb+tx;
        if(REMAP){
            if(n < OUT_DIM && k < Kpad){
                int f = n/23, j = n - 23*f;
                out[(size_t)(f*32+j)*Kpad+k] = f2bf(t[tx][ty+i]);
            }
        } else if(n<Npad && k<Kpad){
            out[(size_t)n*Kpad+k] = f2bf(t[tx][ty+i]);
        }
    }
}

__global__ void reorder_bias(const float* __restrict__ bo, float* __restrict__ bo2){
    int idx = blockIdx.x*256 + threadIdx.x;
    if(idx >= 3*OUT_DIM) return;
    int l = idx/OUT_DIM, n = idx%OUT_DIM;
    int f = n/23, j = n - 23*f;
    bo2[(size_t)l*WO2_ROWS + f*32 + j] = bo[idx];
}

// zot[f][row] = z2[row][2f+1]
__global__ void transpose_odd(const float* __restrict__ z2, float* __restrict__ zot){
    __shared__ float t[32][33];
    int fb = blockIdx.x*32, rb = blockIdx.y*32;
    int tx = threadIdx.x, ty = threadIdx.y;
#pragma unroll
    for(int i=0;i<32;i+=8){
        int r = rb+ty+i, f = fb+tx;
        t[ty+i][tx] = (f<F_DIM) ? z2[(size_t)r*D_DIM + 2*f + 1] : 0.f;
    }
    __syncthreads();
#pragma unroll
    for(int i=0;i<32;i+=8){
        int f = fb+ty+i, r = rb+tx;
        if(f<F_DIM) zot[(size_t)f*B_ROWS + r] = t[tx][ty+i];
    }
}

// ------------------------------ bf16 MFMA gemm -----------------------------
template<int OUTBF, int XSWAP>
__global__ __launch_bounds__(256)
void gemm_mfma(const ushort_t* __restrict__ A, const ushort_t* __restrict__ Bt,
               const float* __restrict__ bias, void* __restrict__ Cv,
               int M, int N, int Kpad, long sA, long sB, long sC){
    A  += (size_t)blockIdx.z*sA;
    Bt += (size_t)blockIdx.z*sB;
    __shared__ ushort_t As[128][72];
    __shared__ ushort_t Bs[128][72];
    int tid = threadIdx.x;
    int row0 = (XSWAP ? blockIdx.x : blockIdx.y)*128;
    int col0 = (XSWAP ? blockIdx.y : blockIdx.x)*128;
    int wave = tid>>6, lane = tid&63;
    int wm = wave&1, wn = wave>>1;
    int lm = lane&15, quad = lane>>4;
    f32x4 acc[4][4] = {};
    for(int k0=0; k0<Kpad; k0+=64){
#pragma unroll
        for(int it=0; it<4; it++){
            int c = tid + it*256;
            int r = c>>3, c8 = (c&7)*8;
            *(ushort8*)&As[r][c8] = *(const ushort8*)(A + (size_t)(row0+r)*Kpad + k0 + c8);
            *(ushort8*)&Bs[r][c8] = *(const ushort8*)(Bt + (size_t)(col0+r)*Kpad + k0 + c8);
        }
        __syncthreads();
#pragma unroll
        for(int ks=0; ks<2; ks++){
            short8 af[4], bfr[4];
#pragma unroll
            for(int i=0;i<4;i++){
                af[i]  = *(const short8*)&As[wm*64 + i*16 + lm][ks*32 + quad*8];
                bfr[i] = *(const short8*)&Bs[wn*64 + i*16 + lm][ks*32 + quad*8];
            }
#pragma unroll
            for(int i=0;i<4;i++)
#pragma unroll
                for(int j=0;j<4;j++)
                    acc[i][j] = __builtin_amdgcn_mfma_f32_16x16x32_bf16(af[i], bfr[j], acc[i][j], 0, 0, 0);
        }
        __syncthreads();
    }
#pragma unroll
    for(int i=0;i<4;i++){
        int rbase = row0 + wm*64 + i*16 + quad*4;
#pragma unroll
        for(int j=0;j<4;j++){
            int gc = col0 + wn*64 + j*16 + lm;
            if(gc >= N) continue;
            float bv = bias[gc];
#pragma unroll
            for(int r=0;r<4;r++){
                int gr = rbase + r;
                float v = acc[i][j][r] + bv;
                if(OUTBF) ((ushort_t*)Cv + (size_t)blockIdx.z*sC)[(size_t)gr*N+gc] = f2bf(v);
                else      ((float*)Cv + (size_t)blockIdx.z*sC)[(size_t)gr*N+gc] = v;
            }
        }
    }
}

// ------------------------------ fused resnet -------------------------------
__global__ __launch_bounds__(256)
void resnet_fused(const ushort_t* __restrict__ identb,
                  const ushort_t* __restrict__ WiT,
                  const float* __restrict__ bi,
                  const ushort_t* __restrict__ WbT,
                  const float* __restrict__ bb,
                  ushort_t* __restrict__ tb){
    __shared__ __align__(16) char smem[(64*136 + 128*136)*2];
    ushort_t (*As2)[136] = (ushort_t(*)[136])smem;
    ushort_t (*Ws)[136]  = (ushort_t(*)[136])(smem + 64*136*2);
    ushort_t (*As1)[72]  = (ushort_t(*)[72])smem;
    ushort_t (*Bs1)[72]  = (ushort_t(*)[72])(smem + 64*136*2);
    int tid = threadIdx.x, wave = tid>>6, lane = tid&63;
    int lm = lane&15, quad = lane>>4;
    int r0 = blockIdx.x*64;
    f32x4 cur[8] = {};
    f32x4 tsv[8];
    for(int k0=0; k0<F_PAD; k0+=64){
#pragma unroll
        for(int it=0; it<2; it++){
            int v = tid + it*256; int r = v>>3, c8 = (v&7)*8;
            *(ushort8*)&As1[r][c8] = *(const ushort8*)(identb + (size_t)(r0+r)*F_PAD + k0 + c8);
        }
#pragma unroll
        for(int it=0; it<4; it++){
            int v = tid + it*256; int n = v>>3, c8 = (v&7)*8;
            *(ushort8*)&Bs1[n][c8] = *(const ushort8*)(WiT + (size_t)n*F_PAD + k0 + c8);
        }
        __syncthreads();
#pragma unroll
        for(int ks=0; ks<2; ks++){
            short8 af = *(const short8*)&As1[wave*16 + lm][ks*32 + quad*8];
#pragma unroll
            for(int j=0;j<8;j++){
                short8 bf = *(const short8*)&Bs1[j*16 + lm][ks*32 + quad*8];
                cur[j] = __builtin_amdgcn_mfma_f32_16x16x32_bf16(af, bf, cur[j], 0, 0, 0);
            }
        }
        __syncthreads();
    }
#pragma unroll
    for(int j=0;j<8;j++){
        float bv = bi[j*16 + lm];
#pragma unroll
        for(int r=0;r<4;r++) cur[j][r] += bv;
        tsv[j] = cur[j];
    }
    for(int st=0; st<4; st++){
#pragma unroll
        for(int j=0;j<8;j++)
#pragma unroll
            for(int r=0;r<4;r++)
                As2[wave*16 + quad*4 + r][j*16 + lm] = f2bf(fmaxf(cur[j][r], 0.f));
#pragma unroll
        for(int it=0; it<8; it++){
            int v = tid + it*256; int n = v>>4, c8 = (v&15)*8;
            *(ushort8*)&Ws[n][c8] = *(const ushort8*)(WbT + (size_t)st*128*128 + (size_t)n*128 + c8);
        }
        __syncthreads();
        f32x4 acc[8] = {};
#pragma unroll
        for(int ks=0; ks<4; ks++){
            short8 af = *(const short8*)&As2[wave*16 + lm][ks*32 + quad*8];
#pragma unroll
            for(int j=0;j<8;j++){
                short8 bf = *(const short8*)&Ws[j*16 + lm][ks*32 + quad*8];
                acc[j] = __builtin_amdgcn_mfma_f32_16x16x32_bf16(af, bf, acc[j], 0, 0, 0);
            }
        }
        __syncthreads();
#pragma unroll
        for(int j=0;j<8;j++){
            float bv = bb[st*128 + j*16 + lm];
#pragma unroll
            for(int r=0;r<4;r++) acc[j][r] += bv;
        }
        if(st==1 || st==3){
#pragma unroll
            for(int j=0;j<8;j++){
#pragma unroll
                for(int r=0;r<4;r++) acc[j][r] += tsv[j][r];
                tsv[j] = acc[j];
            }
        }
#pragma unroll
        for(int j=0;j<8;j++) cur[j] = acc[j];
    }
#pragma unroll
    for(int j=0;j<8;j++)
#pragma unroll
        for(int r=0;r<4;r++)
            tb[(size_t)(r0 + wave*16 + quad*4 + r)*HID_DIM + j*16 + lm] = f2bf(cur[j][r]);
}

// ----------------------- fused Wo gemm + trans spline ----------------------
// R11: launch_bounds(256,2) -> VGPR cap 256, no scratch spills in the spline
// phase (R7-R10 showed ~60MB/dispatch phantom scratch traffic at VGPR=72).
__global__ __launch_bounds__(256, 2)
void wo_spline(const ushort_t* __restrict__ tb,
               const ushort_t* __restrict__ Wo2,
               const float* __restrict__ bo2,
               const float* __restrict__ zot,
               ushort_t* __restrict__ tout,
               float* __restrict__ ldp){
    __shared__ __align__(16) char smem[128*72*2*2];
    __shared__ float ldred[128];
    ushort_t (*As)[72] = (ushort_t(*)[72])smem;
    ushort_t (*Bs)[72] = (ushort_t(*)[72])(smem + 128*72*2);
    ushort_t (*P)[138] = (ushort_t(*)[138])smem;
    int tid = threadIdx.x;
    int row0 = blockIdx.x*128;
    int colt = blockIdx.y;
    int col0 = colt*128;
    int wave = tid>>6, lane = tid&63;
    int wm = wave&1, wn = wave>>1;
    int lm = lane&15, quad = lane>>4;
    f32x4 acc[4][4] = {};
    for(int k0=0; k0<HID_DIM; k0+=64){
#pragma unroll
        for(int it=0; it<4; it++){
            int c = tid + it*256;
            int r = c>>3, c8 = (c&7)*8;
            *(ushort8*)&As[r][c8] = *(const ushort8*)(tb + (size_t)(row0+r)*HID_DIM + k0 + c8);
            *(ushort8*)&Bs[r][c8] = *(const ushort8*)(Wo2 + (size_t)(col0+r)*HID_DIM + k0 + c8);
        }
        __syncthreads();
#pragma unroll
        for(int ks=0; ks<2; ks++){
            short8 af[4], bfr[4];
#pragma unroll
            for(int i=0;i<4;i++){
                af[i]  = *(const short8*)&As[wm*64 + i*16 + lm][ks*32 + quad*8];
                bfr[i] = *(const short8*)&Bs[wn*64 + i*16 + lm][ks*32 + quad*8];
            }
#pragma unroll
            for(int i=0;i<4;i++)
#pragma unroll
                for(int j=0;j<4;j++)
                    acc[i][j] = __builtin_amdgcn_mfma_f32_16x16x32_bf16(af[i], bfr[j], acc[i][j], 0, 0, 0);
        }
        __syncthreads();
    }
#pragma unroll
    for(int j=0;j<4;j++){
        int cl = wn*64 + j*16 + lm;
        float bv = bo2[col0 + cl];
#pragma unroll
        for(int i=0;i<4;i++){
            int rl = wm*64 + i*16 + quad*4;
#pragma unroll
            for(int r=0;r<4;r++) P[rl+r][cl] = f2bf(acc[i][j][r] + bv);
        }
    }
    __syncthreads();
    int row = tid & 127;
    int fbase = colt*4;
    float ldsum = 0.f;
#pragma unroll
    for(int e=0;e<2;e++){
        int feat = (tid>>7) + e*2;
        int fg = fbase + feat;
        if(fg < F_DIM){
            float xv = zot[(size_t)fg*B_ROWS + row0 + row];
            const ushort_t* q = &P[row][feat*32];
            float uw[8], uh[8];
#pragma unroll
            for(int c=0;c<8;c++){ uw[c] = bf2f(q[c])*RSQRT_HID; uh[c] = bf2f(q[8+c])*RSQRT_HID; }
            float cw[9], w[8], ch[9], h[8], d[9];
            knots_from_u(uw, cw, w);
            knots_from_u(uh, ch, h);
            d[0]=1.0f; d[8]=1.0f;
#pragma unroll
            for(int c=0;c<7;c++) d[c+1] = MIND_C + softplusf(bf2f(q[16+c]));
            float o, l;
            rqs_inv(xv, cw, w, ch, h, d, o, l);
            tout[(size_t)fg*B_ROWS + row0 + row] = f2bf(o);
            ldsum += l;
        }
    }
    if(tid >= 128) ldred[tid-128] = ldsum;
    __syncthreads();
    if(tid < 128) ldp[(size_t)colt*B_ROWS + row0 + tid] = ldsum + ldred[tid];
}

// ------------------------------ assemble -----------------------------------
__global__ __launch_bounds__(256)
void assemble_kernel(const ushort_t* __restrict__ identb,
                     const ushort_t* __restrict__ tout,
                     const float* __restrict__ ldp,
                     ushort_t* __restrict__ znb,
                     float* __restrict__ lq){
    __shared__ ushort_t T[F_DIM][65];
    int r0 = blockIdx.x*64;
    int tid = threadIdx.x;
    for(int idx = tid; idx < F_DIM*64; idx += 256){
        int f = idx>>6, r = idx&63;
        T[f][r] = tout[(size_t)f*B_ROWS + r0 + r];
    }
    float s = 0.f;
    if(tid < 64){
        for(int j=0;j<NCOLT;j++) s += ldp[(size_t)j*B_ROWS + r0 + tid];
    }
    __syncthreads();
    if(tid < 64) lq[r0+tid] += s;
    for(int sidx = tid; sidx < 64*(D_PAD/8); sidx += 256){
        int row = sidx/(D_PAD/8), c8 = sidx%(D_PAD/8);
        int colb = c8*8;
        ushort_t u[8];
#pragma unroll
        for(int k=0;k<8;k++){
            int col = colb + k;
            ushort_t v = 0;
            if(col < D_DIM){
                int f = col>>1;
                v = (col&1) ? T[f][row] : identb[(size_t)(r0+row)*F_PAD + f];
            }
            u[k] = v;
        }
        *(ushort8*)&znb[(size_t)(r0+row)*D_PAD + colb] = *(ushort8*)u;
    }
}

// --------------------------- spline kernels --------------------------------

__global__ __launch_bounds__(320)
void ident_spline_kernel(const float* __restrict__ z2, const float* __restrict__ knots,
                         int layer, ushort_t* __restrict__ identb,
                         float* __restrict__ lq){
    int row = blockIdx.x; int tid = threadIdx.x;
    float ldv = 0.f;
    if(tid < F_DIM){
        const float* kb = knots + ((size_t)(layer*F_DIM + tid))*43;
        float x = z2[(size_t)row*D_DIM + 2*tid];
        float o, l;
        rqs_inv(x, kb, kb+9, kb+17, kb+26, kb+34, o, l);
        identb[(size_t)row*F_PAD + tid] = f2bf(o);
        ldv = l;
    } else {
        identb[(size_t)row*F_PAD + tid] = 0;
    }
    __shared__ float sm[5];
    float v = ldv;
#pragma unroll
    for(int o=32;o>0;o>>=1) v += __shfl_down(v, o);
    if((tid&63)==0) sm[tid>>6]=v;
    __syncthreads();
    if(tid==0) lq[row] += sm[0]+sm[1]+sm[2]+sm[3]+sm[4];
}

__global__ __launch_bounds__(320)
void finalize_kernel(const ushort_t* __restrict__ zb, const float* __restrict__ loc,
                     const float* __restrict__ lsc, const float* __restrict__ lq,
                     const float* __restrict__ logdiag, float* __restrict__ out){
    int row = blockIdx.x; int tid = threadIdx.x;
    float s = 0.f;
    for(int k=tid; k<D_DIM; k+=320){
        float l = lsc[k];
        float diff = (bf2f(zb[(size_t)row*D_PAD+k])-loc[k])*__expf(-l);
        s += l + 0.5f*diff*diff;
    }
    __shared__ float sm[5];
#pragma unroll
    for(int o=32;o>0;o>>=1) s += __shfl_down(s, o);
    if((tid&63)==0) sm[tid>>6]=s;
    __syncthreads();
    if(tid==0){
        float tot = sm[0]+sm[1]+sm[2]+sm[3]+sm[4];
        out[row] = lq[row] + logdiag[0] - 275.f*1.8378770664f - tot;
    }
}

// ---------------------------------------------------------------------------

extern "C" void kernel_launch(void* const* d_in, const int* in_sizes, int n_in,
                              void* d_out, int out_size, void* d_ws, size_t ws_size,
                              hipStream_t stream){
    const float* x        = (const float*)d_in[0];
    const float* loc      = (const float*)d_in[1];
    const float* lsc      = (const float*)d_in[2];
    const float* Wi       = (const float*)d_in[3];
    const float* bi       = (const float*)d_in[4];
    const float* Wb       = (const float*)d_in[5];
    const float* bb       = (const float*)d_in[6];
    const float* Wo       = (const float*)d_in[7];
    const float* bo       = (const float*)d_in[8];
    const float* uw_u     = (const float*)d_in[9];
    const float* uh_u     = (const float*)d_in[10];
    const float* ud_u     = (const float*)d_in[11];
    const float* lu_lower = (const float*)d_in[12];
    const float* lu_upper = (const float*)d_in[13];
    const float* lu_ud    = (const float*)d_in[14];
    const float* lu_b     = (const float*)d_in[15];
    const int*   perms    = (const int*)d_in[16];
    float* out = (float*)d_out;

    char* base = (char*)d_ws;
    size_t off = 0;
    auto alloc = [&](size_t bytes)->char*{
        char* p = base + off;
        off += (bytes + 255) & ~(size_t)255;
        return p;
    };
    float* lq      = (float*)alloc(B_ROWS*4);
    float* zbias   = (float*)alloc(D_PAD*4);
    float* logdiag = (float*)alloc(64*4);
    float* knots   = (float*)alloc((size_t)3*F_DIM*43*4);
    float* z2      = (float*)alloc((size_t)B_ROWS*D_DIM*4);
    float* zot     = (float*)alloc((size_t)F_DIM*B_ROWS*4);
    float* bo2     = (float*)alloc((size_t)3*WO2_ROWS*4);
    float* ldp     = (float*)alloc((size_t)NCOLT*B_ROWS*4);
    ushort_t* xb   = (ushort_t*)alloc((size_t)B_ROWS*D_PAD*2);
    ushort_t* zbf0 = (ushort_t*)alloc((size_t)B_ROWS*D_PAD*2);
    ushort_t* zbf1 = (ushort_t*)alloc((size_t)B_ROWS*D_PAD*2);
    ushort_t* tout = (ushort_t*)alloc((size_t)F_DIM*B_ROWS*2);
    ushort_t* Lmb  = (ushort_t*)alloc((size_t)3*N_PAD_A*D_PAD*2);
    ushort_t* UpTb = (ushort_t*)alloc((size_t)3*N_PAD_A*D_PAD*2);
    ushort_t* Apb  = (ushort_t*)alloc((size_t)3*N_PAD_A*D_PAD*2);
    ushort_t* identb=(ushort_t*)alloc((size_t)B_ROWS*F_PAD*2);
    ushort_t* tb   = (ushort_t*)alloc((size_t)B_ROWS*HID_DIM*2);
    ushort_t* WiT  = (ushort_t*)alloc((size_t)3*HID_DIM*F_PAD*2);
    ushort_t* WbT  = (ushort_t*)alloc((size_t)3*4*HID_DIM*HID_DIM*2);
    ushort_t* Wo2  = (ushort_t*)alloc((size_t)3*WO2_ROWS*HID_DIM*2);

    hipMemsetAsync(lq, 0, B_ROWS*sizeof(float), stream);
    hipMemsetAsync(zbias, 0, D_PAD*sizeof(float), stream);
    hipMemsetAsync(Lmb, 0, (size_t)3*N_PAD_A*D_PAD*2, stream);
    hipMemsetAsync(UpTb, 0, (size_t)3*N_PAD_A*D_PAD*2, stream);
    hipMemsetAsync(Wo2, 0, (size_t)3*WO2_ROWS*HID_DIM*2, stream);
    hipMemsetAsync(bo2, 0, (size_t)3*WO2_ROWS*4, stream);
    build_knots_kernel<<<dim3((3*F_DIM+255)/256), dim3(256), 0, stream>>>(uw_u, uh_u, ud_u, knots);
    logdiag_kernel<<<dim3(1), dim3(256), 0, stream>>>(lu_ud, logdiag);
    convert_pad<<<dim3((B_ROWS*D_PAD+255)/256), dim3(256), 0, stream>>>(
        x, xb, B_ROWS, D_DIM, B_ROWS, D_PAD);
    build_LU_bf16<<<dim3((D_DIM+255)/256, D_DIM, 3), dim3(256), 0, stream>>>(
        lu_lower, lu_upper, lu_ud, perms, Lmb, UpTb);
    gemm_mfma<1,0><<<dim3(5, 5, 3), dim3(256), 0, stream>>>(
        Lmb, UpTb, zbias, Apb, N_PAD_A, D_PAD, D_PAD,
        (long)N_PAD_A*D_PAD, (long)N_PAD_A*D_PAD, (long)N_PAD_A*D_PAD);
    dim3 tthr(32,8);
    transpose_convert<0><<<dim3(F_PAD/32, HID_DIM/32, 3), tthr, 0, stream>>>(
        Wi, WiT, F_DIM, HID_DIM, F_PAD, HID_DIM, (long)F_DIM*HID_DIM, (long)F_PAD*HID_DIM);
    transpose_convert<0><<<dim3(HID_DIM/32, HID_DIM/32, 12), tthr, 0, stream>>>(
        Wb, WbT, HID_DIM, HID_DIM, HID_DIM, HID_DIM, (long)HID_DIM*HID_DIM, (long)HID_DIM*HID_DIM);
    transpose_convert<1><<<dim3(HID_DIM/32, OUT_PAD/32, 3), tthr, 0, stream>>>(
        Wo, Wo2, HID_DIM, OUT_DIM, HID_DIM, OUT_PAD, (long)HID_DIM*OUT_DIM, (long)WO2_ROWS*HID_DIM);
    reorder_bias<<<dim3((3*OUT_DIM+255)/256), dim3(256), 0, stream>>>(bo, bo2);

    const ushort_t* zcur_b = xb;
    ushort_t* zbf[2] = {zbf0, zbf1};
    int zi = 0;

    for(int it=0; it<3; ++it){
        int i = 2 - it;

        gemm_mfma<0,1><<<dim3(B_ROWS/128, N_PAD_A/128), dim3(256), 0, stream>>>(
            zcur_b, Apb + (size_t)i*N_PAD_A*D_PAD, lu_b + (size_t)i*D_DIM,
            z2, B_ROWS, D_DIM, D_PAD, 0, 0, 0);

        transpose_odd<<<dim3((F_DIM+31)/32, B_ROWS/32), tthr, 0, stream>>>(z2, zot);

        ident_spline_kernel<<<dim3(B_ROWS), dim3(320), 0, stream>>>(
            z2, knots, i, identb, lq);

        resnet_fused<<<dim3(B_ROWS/64), dim3(256), 0, stream>>>(
            identb, WiT + (size_t)i*HID_DIM*F_PAD, bi + (size_t)i*HID_DIM,
            WbT + (size_t)i*4*HID_DIM*HID_DIM, bb + (size_t)i*4*HID_DIM, tb);

        wo_spline<<<dim3(B_ROWS/128, NCOLT), dim3(256), 0, stream>>>(
            tb, Wo2 + (size_t)i*WO2_ROWS*HID_DIM, bo2 + (size_t)i*WO2_ROWS,
            zot, tout, ldp);

        assemble_kernel<<<dim3(B_ROWS/64), dim3(256), 0, stream>>>(
            identb, tout, ldp, zbf[zi], lq);

        zcur_b = zbf[zi];
        zi ^= 1;
    }

    finalize_kernel<<<dim3(B_ROWS), dim3(320), 0, stream>>>(
        zcur_b, loc, lsc, lq, logdiag, out);
}